// Round 1
// baseline (2692.930 us; speedup 1.0000x reference)
//
#include <hip/hip_runtime.h>
#include <math.h>

#define QDIM 4096
#define NQ 12
#define QBATCH 2048

union F4 { float4 v; float f[4]; };

// ---------------------------------------------------------------------------
// Expand: per batch row, build encoded state v[b, idx] = prod_q col2[q][bit_{11-q}(idx)]
// a_q = cos(x/2) e^{-i x^2/2}, b_q = sin(x/2) e^{+i x^2/2}
// ---------------------------------------------------------------------------
__global__ __launch_bounds__(256) void expand_kernel(
    const float* __restrict__ inputs, float* __restrict__ vRe, float* __restrict__ vIm)
{
    __shared__ float ab[NQ][4]; // a_re, a_im, b_re, b_im
    const int b = blockIdx.x;
    const int tid = threadIdx.x;
    if (tid < NQ) {
        float x = inputs[b * NQ + tid];
        float ry = 0.5f * x;
        float rz = 0.5f * x * x;
        float ca = cosf(ry), sa = sinf(ry), cz = cosf(rz), sz = sinf(rz);
        ab[tid][0] = ca * cz;  ab[tid][1] = -ca * sz;   // a
        ab[tid][2] = sa * cz;  ab[tid][3] =  sa * sz;   // b
    }
    __syncthreads();
    for (int idx = tid; idx < QDIM; idx += 256) {
        float pr = 1.f, pi = 0.f;
#pragma unroll
        for (int q = 0; q < NQ; ++q) {
            int bit = (idx >> (11 - q)) & 1;
            float cr = ab[q][bit * 2 + 0];
            float ci = ab[q][bit * 2 + 1];
            float nr = pr * cr - pi * ci;
            float ni = pr * ci + pi * cr;
            pr = nr; pi = ni;
        }
        vRe[(size_t)b * QDIM + idx] = pr;
        vIm[(size_t)b * QDIM + idx] = pi;
    }
}

// ---------------------------------------------------------------------------
// GEMM: C[m,n] = sum_k A[m,k] * B[n,k], complex A (2 planes) x real B (= E rows).
// If FUSE_G: B[n,k] = c0*E[n,k] + c1*E[n+2048,k]  (final-rot fold, N=2048)
// BM=BN=64, BK=16, 256 threads, 4x4 thread tile per plane.
// ---------------------------------------------------------------------------
template <bool FUSE_G>
__global__ __launch_bounds__(256) void gemm_kernel(
    const float* __restrict__ Are, const float* __restrict__ Aim,
    const float* __restrict__ E, const float* __restrict__ wgt,
    float* __restrict__ Cre, float* __restrict__ Cim,
    int M, int N)
{
    const int K = QDIM;
    __shared__ __align__(16) float Asr[16][68];
    __shared__ __align__(16) float Asi[16][68];
    __shared__ __align__(16) float Bs[16][68];

    const int tid = threadIdx.x;
    const int bn0 = blockIdx.x * 64;
    const int bm0 = blockIdx.y * 64;

    float c0 = 1.f, c1 = 0.f;
    if (FUSE_G) {
        float th = 0.5f * (wgt[0] + wgt[1] + wgt[2]);
        c0 = cosf(th);
        c1 = -sinf(th);
    }

    const int lr = tid >> 2;         // 0..63 tile row
    const int lk = (tid & 3) * 4;    // 0,4,8,12 k-offset
    const int ty = tid >> 4, tx = tid & 15;
    const int tm = ty * 4, tn = tx * 4;

    float accRe[4][4] = {};
    float accIm[4][4] = {};

    for (int kk = 0; kk < K; kk += 16) {
        F4 ar4, ai4, b4;
        ar4.v = *(const float4*)&Are[(size_t)(bm0 + lr) * K + kk + lk];
        ai4.v = *(const float4*)&Aim[(size_t)(bm0 + lr) * K + kk + lk];
        if (FUSE_G) {
            F4 e0, e1;
            e0.v = *(const float4*)&E[(size_t)(bn0 + lr) * K + kk + lk];
            e1.v = *(const float4*)&E[(size_t)(bn0 + lr + 2048) * K + kk + lk];
#pragma unroll
            for (int j = 0; j < 4; ++j) b4.f[j] = c0 * e0.f[j] + c1 * e1.f[j];
        } else {
            b4.v = *(const float4*)&E[(size_t)(bn0 + lr) * K + kk + lk];
        }
        __syncthreads();  // previous iteration's LDS reads complete
#pragma unroll
        for (int j = 0; j < 4; ++j) {
            Asr[lk + j][lr] = ar4.f[j];
            Asi[lk + j][lr] = ai4.f[j];
            Bs[lk + j][lr]  = b4.f[j];
        }
        __syncthreads();
#pragma unroll
        for (int k = 0; k < 16; ++k) {
            F4 a_r, a_i, b_v;
            a_r.v = *(const float4*)&Asr[k][tm];
            a_i.v = *(const float4*)&Asi[k][tm];
            b_v.v = *(const float4*)&Bs[k][tn];
#pragma unroll
            for (int i = 0; i < 4; ++i)
#pragma unroll
                for (int j = 0; j < 4; ++j) {
                    accRe[i][j] = fmaf(a_r.f[i], b_v.f[j], accRe[i][j]);
                    accIm[i][j] = fmaf(a_i.f[i], b_v.f[j], accIm[i][j]);
                }
        }
    }

#pragma unroll
    for (int i = 0; i < 4; ++i) {
        F4 r, s;
#pragma unroll
        for (int j = 0; j < 4; ++j) { r.f[j] = accRe[i][j]; s.f[j] = accIm[i][j]; }
        *(float4*)&Cre[(size_t)(bm0 + tm + i) * N + bn0 + tn] = r.v;
        *(float4*)&Cim[(size_t)(bm0 + tm + i) * N + bn0 + tn] = s.v;
    }
}

// ---------------------------------------------------------------------------
// Butterfly: apply R (Kronecker of 12 2x2 complex mats) to each row, in LDS.
// mats[q] = Rx(w[3+q]) @ Rz(w[15+q]); qubit q acts on bit p = 11-q.
// ---------------------------------------------------------------------------
__global__ __launch_bounds__(256) void butterfly_kernel(
    const float* __restrict__ uRe, const float* __restrict__ uIm,
    const float* __restrict__ wgt,
    float* __restrict__ oRe, float* __restrict__ oIm)
{
    __shared__ float sRe[QDIM];
    __shared__ float sIm[QDIM];
    __shared__ float mats[NQ][8];
    const int b = blockIdx.x;
    const int tid = threadIdx.x;

    if (tid < NQ) {
        float tx = 0.5f * wgt[3 + tid];
        float tz = 0.5f * wgt[15 + tid];
        float c = cosf(tx), s = sinf(tx), cz = cosf(tz), sz = sinf(tz);
        // m00 = c e^{-i tz}; m01 = -i s e^{+i tz}; m10 = -i s e^{-i tz}; m11 = c e^{+i tz}
        mats[tid][0] =  c * cz;  mats[tid][1] = -c * sz;
        mats[tid][2] =  s * sz;  mats[tid][3] = -s * cz;
        mats[tid][4] = -s * sz;  mats[tid][5] = -s * cz;
        mats[tid][6] =  c * cz;  mats[tid][7] =  c * sz;
    }
    for (int v = tid; v < QDIM / 4; v += 256) {
        *(float4*)&sRe[v * 4] = *(const float4*)&uRe[(size_t)b * QDIM + v * 4];
        *(float4*)&sIm[v * 4] = *(const float4*)&uIm[(size_t)b * QDIM + v * 4];
    }
    __syncthreads();

    for (int p = 0; p < NQ; ++p) {
        const int q = 11 - p;
        const float m00r = mats[q][0], m00i = mats[q][1];
        const float m01r = mats[q][2], m01i = mats[q][3];
        const float m10r = mats[q][4], m10i = mats[q][5];
        const float m11r = mats[q][6], m11i = mats[q][7];
        for (int t = tid; t < QDIM / 2; t += 256) {
            int i0 = ((t >> p) << (p + 1)) | (t & ((1 << p) - 1));
            int i1 = i0 | (1 << p);
            float x0r = sRe[i0], x0i = sIm[i0];
            float x1r = sRe[i1], x1i = sIm[i1];
            sRe[i0] = m00r * x0r - m00i * x0i + m01r * x1r - m01i * x1i;
            sIm[i0] = m00r * x0i + m00i * x0r + m01r * x1i + m01i * x1r;
            sRe[i1] = m10r * x0r - m10i * x0i + m11r * x1r - m11i * x1i;
            sIm[i1] = m10r * x0i + m10i * x0r + m11r * x1i + m11i * x1r;
        }
        __syncthreads();
    }

    for (int v = tid; v < QDIM / 4; v += 256) {
        *(float4*)&oRe[(size_t)b * QDIM + v * 4] = *(float4*)&sRe[v * 4];
        *(float4*)&oIm[(size_t)b * QDIM + v * 4] = *(float4*)&sIm[v * 4];
    }
}

// ---------------------------------------------------------------------------
// Reduce: out[b] = sum_{i<2048} |u3[b,i]|^2
// ---------------------------------------------------------------------------
__global__ __launch_bounds__(256) void reduce_kernel(
    const float* __restrict__ uRe, const float* __restrict__ uIm,
    float* __restrict__ out)
{
    const int b = blockIdx.x;
    const int tid = threadIdx.x;
    float sum = 0.f;
    for (int i = tid; i < 2048; i += 256) {
        float r = uRe[(size_t)b * 2048 + i];
        float m = uIm[(size_t)b * 2048 + i];
        sum += r * r + m * m;
    }
#pragma unroll
    for (int off = 32; off > 0; off >>= 1) sum += __shfl_down(sum, off, 64);
    __shared__ float wsum[4];
    int wid = tid >> 6, lane = tid & 63;
    if (lane == 0) wsum[wid] = sum;
    __syncthreads();
    if (tid == 0) out[b] = wsum[0] + wsum[1] + wsum[2] + wsum[3];
}

// ---------------------------------------------------------------------------
extern "C" void kernel_launch(void* const* d_in, const int* in_sizes, int n_in,
                              void* d_out, int out_size, void* d_ws, size_t ws_size,
                              hipStream_t stream)
{
    const float* inputs = (const float*)d_in[0];   // [2048, 12]
    const float* weight = (const float*)d_in[1];   // [27]
    const float* E      = (const float*)d_in[2];   // [4096, 4096]
    float* out = (float*)d_out;                    // [2048]

    float* ws = (float*)d_ws;
    const size_t P = (size_t)QBATCH * QDIM;        // 8,388,608 floats per plane
    float* vRe = ws;
    float* vIm = ws + P;
    float* uRe = ws + 2 * P;
    float* uIm = ws + 3 * P;                       // total 128 MiB

    // 1. encode -> v
    expand_kernel<<<QBATCH, 256, 0, stream>>>(inputs, vRe, vIm);
    // 2. u1 = v @ E^T
    gemm_kernel<false><<<dim3(QDIM / 64, QBATCH / 64), 256, 0, stream>>>(
        vRe, vIm, E, weight, uRe, uIm, QBATCH, QDIM);
    // 3. u2 = R u1 (butterflies), back into v buffers
    butterfly_kernel<<<QBATCH, 256, 0, stream>>>(uRe, uIm, weight, vRe, vIm);
    // 4. u3 = u2 @ G^T, G = c0*E[:2048] + c1*E[2048:]  (final-rot folded)
    gemm_kernel<true><<<dim3(2048 / 64, QBATCH / 64), 256, 0, stream>>>(
        vRe, vIm, E, weight, uRe, uIm, QBATCH, 2048);
    // 5. out[b] = sum |u3|^2 over first half
    reduce_kernel<<<QBATCH, 256, 0, stream>>>(uRe, uIm, out);
}

// Round 2
// 448.221 us; speedup vs baseline: 6.0080x; 6.0080x over previous
//
#include <hip/hip_runtime.h>
#include <math.h>

#define QDIM 4096
#define NQ 12
#define QBATCH 2048

typedef _Float16 f16x8 __attribute__((ext_vector_type(8)));
typedef float f32x4 __attribute__((ext_vector_type(4)));

__device__ __forceinline__ void gld_lds16(const void* gptr, void* ldsptr) {
    __builtin_amdgcn_global_load_lds(
        (const __attribute__((address_space(1))) void*)gptr,
        (__attribute__((address_space(3))) void*)ldsptr,
        16, 0, 0);
}

// ---------------------------------------------------------------------------
// conv: Eh = fp16(E); G[n,:] = fp16(c0*E[n,:] + c1*E[n+2048,:])  (final-rot fold)
// ---------------------------------------------------------------------------
__global__ __launch_bounds__(256) void conv_kernel(
    const float* __restrict__ E, const float* __restrict__ wgt,
    _Float16* __restrict__ Eh, _Float16* __restrict__ G)
{
    const size_t NE = (size_t)QDIM * QDIM / 8;     // 2M chunks of 8
    const size_t NG = (size_t)QBATCH * QDIM / 8;   // 1M chunks
    size_t i = (size_t)blockIdx.x * 256 + threadIdx.x;
    if (i < NE) {
        float4 a = ((const float4*)E)[2 * i];
        float4 b = ((const float4*)E)[2 * i + 1];
        f16x8 h = { (_Float16)a.x, (_Float16)a.y, (_Float16)a.z, (_Float16)a.w,
                    (_Float16)b.x, (_Float16)b.y, (_Float16)b.z, (_Float16)b.w };
        ((f16x8*)Eh)[i] = h;
    } else if (i < NE + NG) {
        float th = 0.5f * (wgt[0] + wgt[1] + wgt[2]);
        float c0 = cosf(th), c1 = -sinf(th);
        size_t flat = (i - NE) * 8;
        size_t n = flat >> 12;
        size_t k = flat & (QDIM - 1);
        const float* p0 = E + n * QDIM + k;
        const float* p1 = p0 + (size_t)QBATCH * QDIM;
        float4 a0 = ((const float4*)p0)[0], a1 = ((const float4*)p0)[1];
        float4 b0 = ((const float4*)p1)[0], b1 = ((const float4*)p1)[1];
        f16x8 h = { (_Float16)(c0 * a0.x + c1 * b0.x), (_Float16)(c0 * a0.y + c1 * b0.y),
                    (_Float16)(c0 * a0.z + c1 * b0.z), (_Float16)(c0 * a0.w + c1 * b0.w),
                    (_Float16)(c0 * a1.x + c1 * b1.x), (_Float16)(c0 * a1.y + c1 * b1.y),
                    (_Float16)(c0 * a1.z + c1 * b1.z), (_Float16)(c0 * a1.w + c1 * b1.w) };
        ((f16x8*)G)[i - NE] = h;
    }
}

// ---------------------------------------------------------------------------
// Expand: encoded state -> fp16 A matrix, rows [0,2048)=Re, [2048,4096)=Im
// ---------------------------------------------------------------------------
__global__ __launch_bounds__(256) void expand_kernel(
    const float* __restrict__ inputs, _Float16* __restrict__ A1)
{
    __shared__ float ab[NQ][4];
    const int b = blockIdx.x;
    const int tid = threadIdx.x;
    if (tid < NQ) {
        float x = inputs[b * NQ + tid];
        float ry = 0.5f * x;
        float rz = 0.5f * x * x;
        float ca = cosf(ry), sa = sinf(ry), cz = cosf(rz), sz = sinf(rz);
        ab[tid][0] = ca * cz;  ab[tid][1] = -ca * sz;
        ab[tid][2] = sa * cz;  ab[tid][3] =  sa * sz;
    }
    __syncthreads();
    for (int idx = tid; idx < QDIM; idx += 256) {
        float pr = 1.f, pi = 0.f;
#pragma unroll
        for (int q = 0; q < NQ; ++q) {
            int bit = (idx >> (11 - q)) & 1;
            float cr = ab[q][bit * 2 + 0];
            float ci = ab[q][bit * 2 + 1];
            float nr = pr * cr - pi * ci;
            float ni = pr * ci + pi * cr;
            pr = nr; pi = ni;
        }
        A1[(size_t)b * QDIM + idx] = (_Float16)pr;
        A1[(size_t)(b + QBATCH) * QDIM + idx] = (_Float16)pi;
    }
}

// ---------------------------------------------------------------------------
// MFMA GEMM: C[m,n] = sum_k A[m,k]*B[n,k].  A:[4096][4096] f16, B:[N][4096] f16.
// 128x128 tile, BK=32, 256 thr (4 waves, 2x2), 4x4 MFMA 16x16x32 per wave.
// m97 structure: global_load_lds width16 staging, 2 barriers per K-iter.
// ---------------------------------------------------------------------------
template <typename OUT_T>
__global__ __launch_bounds__(256) void mfma_gemm(
    const _Float16* __restrict__ A, const _Float16* __restrict__ B,
    OUT_T* __restrict__ C, int N)
{
    const int K = QDIM;
    __shared__ __attribute__((aligned(16))) _Float16 As[128 * 32];
    __shared__ __attribute__((aligned(16))) _Float16 Bs[128 * 32];

    const int tid  = threadIdx.x;
    const int wave = tid >> 6;
    const int lane = tid & 63;
    const int bn0 = blockIdx.x * 128;
    const int bm0 = blockIdx.y * 128;
    const int wm = (wave >> 1) * 64;
    const int wn = (wave & 1) * 64;
    const int q = lane >> 4;     // k-quad
    const int r = lane & 15;     // row within 16-tile

    f32x4 acc[4][4];
#pragma unroll
    for (int i = 0; i < 4; ++i)
#pragma unroll
        for (int j = 0; j < 4; ++j) acc[i][j] = (f32x4){0.f, 0.f, 0.f, 0.f};

    // staging: tile is 512 chunks of 16B; chunk c -> row c>>2, byte (c&3)*16.
    // issue0: chunks wave*64+lane; issue1: +256. LDS dest = uniform base + lane*16.
    const int c0i = wave * 64 + lane;
    const int c1i = 256 + wave * 64 + lane;
    const int row0 = c0i >> 2, qb0 = (c0i & 3) * 16;
    const int row1 = c1i >> 2, qb1 = (c1i & 3) * 16;

    const char* gA0 = (const char*)(A + (size_t)(bm0 + row0) * K) + qb0;
    const char* gA1 = (const char*)(A + (size_t)(bm0 + row1) * K) + qb1;
    const char* gB0 = (const char*)(B + (size_t)(bn0 + row0) * K) + qb0;
    const char* gB1 = (const char*)(B + (size_t)(bn0 + row1) * K) + qb1;
    char* lA0 = (char*)As + (wave * 64) * 16;
    char* lA1 = (char*)As + (256 + wave * 64) * 16;
    char* lB0 = (char*)Bs + (wave * 64) * 16;
    char* lB1 = (char*)Bs + (256 + wave * 64) * 16;

    for (int kk = 0; kk < K; kk += 32) {
        gld_lds16(gA0 + kk * 2, lA0);
        gld_lds16(gA1 + kk * 2, lA1);
        gld_lds16(gB0 + kk * 2, lB0);
        gld_lds16(gB1 + kk * 2, lB1);
        __syncthreads();   // drains vmcnt: LDS tiles ready

        f16x8 af[4], bf[4];
#pragma unroll
        for (int i = 0; i < 4; ++i)
            af[i] = *(const f16x8*)&As[(wm + i * 16 + r) * 32 + q * 8];
#pragma unroll
        for (int j = 0; j < 4; ++j)
            bf[j] = *(const f16x8*)&Bs[(wn + j * 16 + r) * 32 + q * 8];
#pragma unroll
        for (int i = 0; i < 4; ++i)
#pragma unroll
            for (int j = 0; j < 4; ++j)
                acc[i][j] = __builtin_amdgcn_mfma_f32_16x16x32_f16(af[i], bf[j], acc[i][j], 0, 0, 0);
        __syncthreads();   // all ds_reads done before next stage overwrites
    }

    // C/D layout: col = lane&15, row = (lane>>4)*4 + reg
#pragma unroll
    for (int i = 0; i < 4; ++i) {
        const int crow = bm0 + wm + i * 16 + q * 4;
#pragma unroll
        for (int rr = 0; rr < 4; ++rr)
#pragma unroll
            for (int j = 0; j < 4; ++j)
                C[(size_t)(crow + rr) * N + bn0 + wn + j * 16 + r] = (OUT_T)acc[i][j][rr];
    }
}

// ---------------------------------------------------------------------------
// Butterfly: apply R (Kronecker of 12 2x2 complex mats) per row in LDS (fp32),
// fp16 in / fp16 out. mats[q] = Rx(w[3+q]) @ Rz(w[15+q]); qubit q acts on bit 11-q.
// ---------------------------------------------------------------------------
__global__ __launch_bounds__(256) void butterfly_kernel(
    const _Float16* __restrict__ u1, const float* __restrict__ wgt,
    _Float16* __restrict__ u2)
{
    __shared__ float sRe[QDIM];
    __shared__ float sIm[QDIM];
    __shared__ float mats[NQ][8];
    const int b = blockIdx.x;
    const int tid = threadIdx.x;

    if (tid < NQ) {
        float tx = 0.5f * wgt[3 + tid];
        float tz = 0.5f * wgt[15 + tid];
        float c = cosf(tx), s = sinf(tx), cz = cosf(tz), sz = sinf(tz);
        mats[tid][0] =  c * cz;  mats[tid][1] = -c * sz;
        mats[tid][2] =  s * sz;  mats[tid][3] = -s * cz;
        mats[tid][4] = -s * sz;  mats[tid][5] = -s * cz;
        mats[tid][6] =  c * cz;  mats[tid][7] =  c * sz;
    }
    const _Float16* pRe = u1 + (size_t)b * QDIM;
    const _Float16* pIm = u1 + (size_t)(b + QBATCH) * QDIM;
    for (int v = tid; v < QDIM / 8; v += 256) {
        f16x8 hr = ((const f16x8*)pRe)[v];
        f16x8 hi = ((const f16x8*)pIm)[v];
#pragma unroll
        for (int j = 0; j < 8; ++j) {
            sRe[v * 8 + j] = (float)hr[j];
            sIm[v * 8 + j] = (float)hi[j];
        }
    }
    __syncthreads();

    for (int p = 0; p < NQ; ++p) {
        const int q = 11 - p;
        const float m00r = mats[q][0], m00i = mats[q][1];
        const float m01r = mats[q][2], m01i = mats[q][3];
        const float m10r = mats[q][4], m10i = mats[q][5];
        const float m11r = mats[q][6], m11i = mats[q][7];
        for (int t = tid; t < QDIM / 2; t += 256) {
            int i0 = ((t >> p) << (p + 1)) | (t & ((1 << p) - 1));
            int i1 = i0 | (1 << p);
            float x0r = sRe[i0], x0i = sIm[i0];
            float x1r = sRe[i1], x1i = sIm[i1];
            sRe[i0] = m00r * x0r - m00i * x0i + m01r * x1r - m01i * x1i;
            sIm[i0] = m00r * x0i + m00i * x0r + m01r * x1i + m01i * x1r;
            sRe[i1] = m10r * x0r - m10i * x0i + m11r * x1r - m11i * x1i;
            sIm[i1] = m10r * x0i + m10i * x0r + m11r * x1i + m11i * x1r;
        }
        __syncthreads();
    }

    _Float16* oRe = u2 + (size_t)b * QDIM;
    _Float16* oIm = u2 + (size_t)(b + QBATCH) * QDIM;
    for (int v = tid; v < QDIM / 8; v += 256) {
        f16x8 hr, hi;
#pragma unroll
        for (int j = 0; j < 8; ++j) {
            hr[j] = (_Float16)sRe[v * 8 + j];
            hi[j] = (_Float16)sIm[v * 8 + j];
        }
        ((f16x8*)oRe)[v] = hr;
        ((f16x8*)oIm)[v] = hi;
    }
}

// ---------------------------------------------------------------------------
// Reduce: out[b] = sum_i u3[b,i]^2 + u3[b+2048,i]^2   (i < 2048)
// ---------------------------------------------------------------------------
__global__ __launch_bounds__(256) void reduce_kernel(
    const float* __restrict__ u3, float* __restrict__ out)
{
    const int b = blockIdx.x;
    const int tid = threadIdx.x;
    const float* re = u3 + (size_t)b * 2048;
    const float* im = u3 + (size_t)(b + QBATCH) * 2048;
    float sum = 0.f;
    for (int i = tid; i < 2048; i += 256) {
        float r = re[i], m = im[i];
        sum += r * r + m * m;
    }
#pragma unroll
    for (int off = 32; off > 0; off >>= 1) sum += __shfl_down(sum, off, 64);
    __shared__ float wsum[4];
    int wid = tid >> 6, lane = tid & 63;
    if (lane == 0) wsum[wid] = sum;
    __syncthreads();
    if (tid == 0) out[b] = wsum[0] + wsum[1] + wsum[2] + wsum[3];
}

// ---------------------------------------------------------------------------
extern "C" void kernel_launch(void* const* d_in, const int* in_sizes, int n_in,
                              void* d_out, int out_size, void* d_ws, size_t ws_size,
                              hipStream_t stream)
{
    const float* inputs = (const float*)d_in[0];   // [2048, 12]
    const float* weight = (const float*)d_in[1];   // [27]
    const float* E      = (const float*)d_in[2];   // [4096, 4096] fp32
    float* out = (float*)d_out;                    // [2048]

    char* ws = (char*)d_ws;
    const size_t MB = 1024 * 1024;
    _Float16* Eh = (_Float16*)(ws + 0);            // 32 MB
    _Float16* G  = (_Float16*)(ws + 32 * MB);      // 16 MB
    _Float16* A1 = (_Float16*)(ws + 48 * MB);      // 32 MB
    _Float16* u1 = (_Float16*)(ws + 80 * MB);      // 32 MB  (total 112 MB)
    _Float16* u2 = (_Float16*)(ws + 0);            // reuse Eh (dead after GEMM1)
    float*    u3 = (float*)(ws + 48 * MB);         // reuse A1 (dead after GEMM1)

    const size_t nconv = (size_t)QDIM * QDIM / 8 + (size_t)QBATCH * QDIM / 8;
    conv_kernel<<<nconv / 256, 256, 0, stream>>>(E, weight, Eh, G);
    expand_kernel<<<QBATCH, 256, 0, stream>>>(inputs, A1);
    mfma_gemm<_Float16><<<dim3(QDIM / 128, 4096 / 128), 256, 0, stream>>>(A1, Eh, u1, QDIM);
    butterfly_kernel<<<QBATCH, 256, 0, stream>>>(u1, weight, u2);
    mfma_gemm<float><<<dim3(2048 / 128, 4096 / 128), 256, 0, stream>>>(u2, G, u3, 2048);
    reduce_kernel<<<QBATCH, 256, 0, stream>>>(u3, out);
}

// Round 3
// 381.894 us; speedup vs baseline: 7.0515x; 1.1737x over previous
//
#include <hip/hip_runtime.h>
#include <math.h>

#define QDIM 4096
#define NQ 12
#define QBATCH 2048

typedef _Float16 f16x8 __attribute__((ext_vector_type(8)));
typedef float f32x4 __attribute__((ext_vector_type(4)));

__device__ __forceinline__ void gld_lds16(const void* gptr, void* ldsptr) {
    __builtin_amdgcn_global_load_lds(
        (const __attribute__((address_space(1))) void*)gptr,
        (__attribute__((address_space(3))) void*)ldsptr,
        16, 0, 0);
}

// ---------------------------------------------------------------------------
// conv: Eh = fp16(E); G[n,:] = fp16(c0*E[n,:] + c1*E[n+2048,:])  (final-rot fold)
// ---------------------------------------------------------------------------
__global__ __launch_bounds__(256) void conv_kernel(
    const float* __restrict__ E, const float* __restrict__ wgt,
    _Float16* __restrict__ Eh, _Float16* __restrict__ G)
{
    const size_t NE = (size_t)QDIM * QDIM / 8;     // 2M chunks of 8
    const size_t NG = (size_t)QBATCH * QDIM / 8;   // 1M chunks
    size_t i = (size_t)blockIdx.x * 256 + threadIdx.x;
    if (i < NE) {
        float4 a = ((const float4*)E)[2 * i];
        float4 b = ((const float4*)E)[2 * i + 1];
        f16x8 h = { (_Float16)a.x, (_Float16)a.y, (_Float16)a.z, (_Float16)a.w,
                    (_Float16)b.x, (_Float16)b.y, (_Float16)b.z, (_Float16)b.w };
        ((f16x8*)Eh)[i] = h;
    } else if (i < NE + NG) {
        float th = 0.5f * (wgt[0] + wgt[1] + wgt[2]);
        float c0 = cosf(th), c1 = -sinf(th);
        size_t flat = (i - NE) * 8;
        size_t n = flat >> 12;
        size_t k = flat & (QDIM - 1);
        const float* p0 = E + n * QDIM + k;
        const float* p1 = p0 + (size_t)QBATCH * QDIM;
        float4 a0 = ((const float4*)p0)[0], a1 = ((const float4*)p0)[1];
        float4 b0 = ((const float4*)p1)[0], b1 = ((const float4*)p1)[1];
        f16x8 h = { (_Float16)(c0 * a0.x + c1 * b0.x), (_Float16)(c0 * a0.y + c1 * b0.y),
                    (_Float16)(c0 * a0.z + c1 * b0.z), (_Float16)(c0 * a0.w + c1 * b0.w),
                    (_Float16)(c0 * a1.x + c1 * b1.x), (_Float16)(c0 * a1.y + c1 * b1.y),
                    (_Float16)(c0 * a1.z + c1 * b1.z), (_Float16)(c0 * a1.w + c1 * b1.w) };
        ((f16x8*)G)[i - NE] = h;
    }
}

// ---------------------------------------------------------------------------
// Expand: encoded state -> fp16 A matrix, rows [0,2048)=Re, [2048,4096)=Im
// ---------------------------------------------------------------------------
__global__ __launch_bounds__(256) void expand_kernel(
    const float* __restrict__ inputs, _Float16* __restrict__ A1)
{
    __shared__ float ab[NQ][4];
    const int b = blockIdx.x;
    const int tid = threadIdx.x;
    if (tid < NQ) {
        float x = inputs[b * NQ + tid];
        float ry = 0.5f * x;
        float rz = 0.5f * x * x;
        float ca = cosf(ry), sa = sinf(ry), cz = cosf(rz), sz = sinf(rz);
        ab[tid][0] = ca * cz;  ab[tid][1] = -ca * sz;
        ab[tid][2] = sa * cz;  ab[tid][3] =  sa * sz;
    }
    __syncthreads();
    for (int idx = tid; idx < QDIM; idx += 256) {
        float pr = 1.f, pi = 0.f;
#pragma unroll
        for (int q = 0; q < NQ; ++q) {
            int bit = (idx >> (11 - q)) & 1;
            float cr = ab[q][bit * 2 + 0];
            float ci = ab[q][bit * 2 + 1];
            float nr = pr * cr - pi * ci;
            float ni = pr * ci + pi * cr;
            pr = nr; pi = ni;
        }
        A1[(size_t)b * QDIM + idx] = (_Float16)pr;
        A1[(size_t)(b + QBATCH) * QDIM + idx] = (_Float16)pi;
    }
}

// ---------------------------------------------------------------------------
// MFMA GEMM: C[m,n] = sum_k A[m,k]*B[n,k].  A:[M][4096] f16, B:[N][4096] f16.
// 128x128 tile, BK=64, 256 thr (4 waves 2x2), 4x4 MFMA 16x16x32 per wave,
// 32 MFMA per barrier pair. XOR-swizzled LDS (conflict-free ds_read_b128):
// LDS chunk position (row, col) holds global chunk (row, col ^ (row&7)).
// FUSE_OUT: no C store; out[row&2047] += sum_n |C[row,n]|^2 (reduce fused).
// ---------------------------------------------------------------------------
template <bool FUSE_OUT>
__global__ __launch_bounds__(256) void mfma_gemm(
    const _Float16* __restrict__ A, const _Float16* __restrict__ B,
    _Float16* __restrict__ C, float* __restrict__ out, int N)
{
    const int K = QDIM;
    __shared__ __attribute__((aligned(16))) _Float16 As[128 * 64];
    __shared__ __attribute__((aligned(16))) _Float16 Bs[128 * 64];

    const int tid  = threadIdx.x;
    const int wave = tid >> 6;
    const int lane = tid & 63;
    const int bn0 = blockIdx.x * 128;
    const int bm0 = blockIdx.y * 128;
    const int wm = (wave >> 1) * 64;
    const int wn = (wave & 1) * 64;
    const int q = lane >> 4;     // k-quad
    const int r = lane & 15;     // row within 16-tile
    const int rx = r & 7;        // swizzle key for fragment reads

    f32x4 acc[4][4];
#pragma unroll
    for (int i = 0; i < 4; ++i)
#pragma unroll
        for (int j = 0; j < 4; ++j) acc[i][j] = (f32x4){0.f, 0.f, 0.f, 0.f};

    // Staging: 1024 16B-chunks per matrix per K-stage; thread handles 4 each.
    // LDS position c = n*256 + tid; fetch global chunk (row, (c&7)^(row&7)).
    const _Float16* gA[4];
    const _Float16* gB[4];
    char* lA[4];
    char* lB[4];
#pragma unroll
    for (int n = 0; n < 4; ++n) {
        int c = n * 256 + tid;
        int row = c >> 3;
        int gcol = (c & 7) ^ (row & 7);
        gA[n] = A + (size_t)(bm0 + row) * K + gcol * 8;
        gB[n] = B + (size_t)(bn0 + row) * K + gcol * 8;
        lA[n] = (char*)As + (n * 256 + wave * 64) * 16;
        lB[n] = (char*)Bs + (n * 256 + wave * 64) * 16;
    }

    for (int kk = 0; kk < K; kk += 64) {
#pragma unroll
        for (int n = 0; n < 4; ++n) {
            gld_lds16(gA[n] + kk, lA[n]);
            gld_lds16(gB[n] + kk, lB[n]);
        }
        __syncthreads();   // drains vmcnt: LDS tiles ready

#pragma unroll
        for (int s = 0; s < 2; ++s) {
            f16x8 af[4], bf[4];
#pragma unroll
            for (int i = 0; i < 4; ++i) {
                int row = wm + i * 16 + r;
                af[i] = *(const f16x8*)&As[(row * 8 + ((s * 4 + q) ^ rx)) * 8];
            }
#pragma unroll
            for (int j = 0; j < 4; ++j) {
                int row = wn + j * 16 + r;
                bf[j] = *(const f16x8*)&Bs[(row * 8 + ((s * 4 + q) ^ rx)) * 8];
            }
#pragma unroll
            for (int i = 0; i < 4; ++i)
#pragma unroll
                for (int j = 0; j < 4; ++j)
                    acc[i][j] = __builtin_amdgcn_mfma_f32_16x16x32_f16(af[i], bf[j], acc[i][j], 0, 0, 0);
        }
        __syncthreads();   // reads done before next stage overwrites
    }

    // C/D layout: col = lane&15 (=r), row = (lane>>4)*4 + reg (=q*4+rr)
    if (!FUSE_OUT) {
#pragma unroll
        for (int i = 0; i < 4; ++i) {
            const int crow = bm0 + wm + i * 16 + q * 4;
#pragma unroll
            for (int rr = 0; rr < 4; ++rr)
#pragma unroll
                for (int j = 0; j < 4; ++j)
                    C[(size_t)(crow + rr) * N + bn0 + wn + j * 16 + r] = (_Float16)acc[i][j][rr];
        }
    } else {
        // fused |.|^2 reduce: sum over this wave's 64 cols, per row
#pragma unroll
        for (int i = 0; i < 4; ++i) {
#pragma unroll
            for (int rr = 0; rr < 4; ++rr) {
                const int row = bm0 + wm + i * 16 + q * 4 + rr;
                float v = 0.f;
#pragma unroll
                for (int j = 0; j < 4; ++j) {
                    float t = acc[i][j][rr];
                    v = fmaf(t, t, v);
                }
                v += __shfl_xor(v, 1, 64);
                v += __shfl_xor(v, 2, 64);
                v += __shfl_xor(v, 4, 64);
                v += __shfl_xor(v, 8, 64);
                if (r == 0) atomicAdd(&out[row & (QBATCH - 1)], v);
            }
        }
    }
}

// ---------------------------------------------------------------------------
// Butterfly: apply R (Kronecker of 12 2x2 complex mats) per row in LDS (fp32),
// fp16 in / fp16 out. mats[q] = Rx(w[3+q]) @ Rz(w[15+q]); qubit q acts on bit 11-q.
// ---------------------------------------------------------------------------
__global__ __launch_bounds__(256) void butterfly_kernel(
    const _Float16* __restrict__ u1, const float* __restrict__ wgt,
    _Float16* __restrict__ u2)
{
    __shared__ float sRe[QDIM];
    __shared__ float sIm[QDIM];
    __shared__ float mats[NQ][8];
    const int b = blockIdx.x;
    const int tid = threadIdx.x;

    if (tid < NQ) {
        float tx = 0.5f * wgt[3 + tid];
        float tz = 0.5f * wgt[15 + tid];
        float c = cosf(tx), s = sinf(tx), cz = cosf(tz), sz = sinf(tz);
        mats[tid][0] =  c * cz;  mats[tid][1] = -c * sz;
        mats[tid][2] =  s * sz;  mats[tid][3] = -s * cz;
        mats[tid][4] = -s * sz;  mats[tid][5] = -s * cz;
        mats[tid][6] =  c * cz;  mats[tid][7] =  c * sz;
    }
    const _Float16* pRe = u1 + (size_t)b * QDIM;
    const _Float16* pIm = u1 + (size_t)(b + QBATCH) * QDIM;
    for (int v = tid; v < QDIM / 8; v += 256) {
        f16x8 hr = ((const f16x8*)pRe)[v];
        f16x8 hi = ((const f16x8*)pIm)[v];
#pragma unroll
        for (int j = 0; j < 8; ++j) {
            sRe[v * 8 + j] = (float)hr[j];
            sIm[v * 8 + j] = (float)hi[j];
        }
    }
    __syncthreads();

    for (int p = 0; p < NQ; ++p) {
        const int q = 11 - p;
        const float m00r = mats[q][0], m00i = mats[q][1];
        const float m01r = mats[q][2], m01i = mats[q][3];
        const float m10r = mats[q][4], m10i = mats[q][5];
        const float m11r = mats[q][6], m11i = mats[q][7];
        for (int t = tid; t < QDIM / 2; t += 256) {
            int i0 = ((t >> p) << (p + 1)) | (t & ((1 << p) - 1));
            int i1 = i0 | (1 << p);
            float x0r = sRe[i0], x0i = sIm[i0];
            float x1r = sRe[i1], x1i = sIm[i1];
            sRe[i0] = m00r * x0r - m00i * x0i + m01r * x1r - m01i * x1i;
            sIm[i0] = m00r * x0i + m00i * x0r + m01r * x1i + m01i * x1r;
            sRe[i1] = m10r * x0r - m10i * x0i + m11r * x1r - m11i * x1i;
            sIm[i1] = m10r * x0i + m10i * x0r + m11r * x1i + m11i * x1r;
        }
        __syncthreads();
    }

    _Float16* oRe = u2 + (size_t)b * QDIM;
    _Float16* oIm = u2 + (size_t)(b + QBATCH) * QDIM;
    for (int v = tid; v < QDIM / 8; v += 256) {
        f16x8 hr, hi;
#pragma unroll
        for (int j = 0; j < 8; ++j) {
            hr[j] = (_Float16)sRe[v * 8 + j];
            hi[j] = (_Float16)sIm[v * 8 + j];
        }
        ((f16x8*)oRe)[v] = hr;
        ((f16x8*)oIm)[v] = hi;
    }
}

// ---------------------------------------------------------------------------
extern "C" void kernel_launch(void* const* d_in, const int* in_sizes, int n_in,
                              void* d_out, int out_size, void* d_ws, size_t ws_size,
                              hipStream_t stream)
{
    const float* inputs = (const float*)d_in[0];   // [2048, 12]
    const float* weight = (const float*)d_in[1];   // [27]
    const float* E      = (const float*)d_in[2];   // [4096, 4096] fp32
    float* out = (float*)d_out;                    // [2048]

    char* ws = (char*)d_ws;
    const size_t MB = 1024 * 1024;
    _Float16* Eh = (_Float16*)(ws + 0);            // 32 MB
    _Float16* G  = (_Float16*)(ws + 32 * MB);      // 16 MB
    _Float16* A1 = (_Float16*)(ws + 48 * MB);      // 32 MB
    _Float16* u1 = (_Float16*)(ws + 80 * MB);      // 32 MB  (total 112 MB)
    _Float16* u2 = (_Float16*)(ws + 0);            // reuse Eh (dead after GEMM1)

    const size_t nconv = (size_t)QDIM * QDIM / 8 + (size_t)QBATCH * QDIM / 8;
    conv_kernel<<<nconv / 256, 256, 0, stream>>>(E, weight, Eh, G);
    expand_kernel<<<QBATCH, 256, 0, stream>>>(inputs, A1);
    // u1 = v @ Eh^T   (M=4096 Re/Im-stacked, N=4096, K=4096)
    mfma_gemm<false><<<dim3(QDIM / 128, 4096 / 128), 256, 0, stream>>>(A1, Eh, u1, nullptr, QDIM);
    // u2 = R u1 (butterflies), into reused buffer
    butterfly_kernel<<<QBATCH, 256, 0, stream>>>(u1, weight, u2);
    // out[b] = sum_n |(u2 @ G^T)[b or b+2048, n]|^2  — reduce fused in epilogue
    hipMemsetAsync(out, 0, QBATCH * sizeof(float), stream);
    mfma_gemm<true><<<dim3(2048 / 128, 4096 / 128), 256, 0, stream>>>(u2, G, nullptr, out, 2048);
}

// Round 5
// 336.686 us; speedup vs baseline: 7.9983x; 1.1343x over previous
//
#include <hip/hip_runtime.h>
#include <math.h>

#define QDIM 4096
#define NQ 12
#define QBATCH 2048

typedef _Float16 f16x8 __attribute__((ext_vector_type(8)));
typedef float f32x4 __attribute__((ext_vector_type(4)));
typedef int i32x4 __attribute__((ext_vector_type(4)));

__device__ __forceinline__ void gld_lds16(const void* gptr, void* ldsptr) {
    __builtin_amdgcn_global_load_lds(
        (const __attribute__((address_space(1))) void*)gptr,
        (__attribute__((address_space(3))) void*)ldsptr,
        16, 0, 0);
}

__device__ __forceinline__ int q8(float x) {
    float y = fminf(fmaxf(x, -127.f), 127.f);
    return (int)rintf(y);
}
__device__ __forceinline__ int pack4_i8(int a, int b, int c, int d) {
    return (a & 0xFF) | ((b & 0xFF) << 8) | ((c & 0xFF) << 16) | ((d & 0xFF) << 24);
}

// ---------------------------------------------------------------------------
// conv (single pass over E): Eh = f16(E) [both halves];
// G8[n,:] = int8( (c0*E[n,:]+c1*E[n+2048,:]) * 127/6 )   (G ~ N(0,1), 6-sigma clip)
// ---------------------------------------------------------------------------
__global__ __launch_bounds__(256) void conv_kernel(
    const float* __restrict__ E, const float* __restrict__ wgt,
    _Float16* __restrict__ Eh, signed char* __restrict__ G8)
{
    float th = 0.5f * (wgt[0] + wgt[1] + wgt[2]);
    float c0 = cosf(th), c1 = -sinf(th);
    const float qs = 127.f / 6.f;
    size_t flat = ((size_t)blockIdx.x * 256 + threadIdx.x) * 8;  // [0, 2048*4096)
    size_t n = flat >> 12;
    size_t k = flat & (QDIM - 1);
    const float* p0 = E + n * QDIM + k;
    const float* p1 = p0 + (size_t)QBATCH * QDIM;
    float4 a0 = ((const float4*)p0)[0], a1 = ((const float4*)p0)[1];
    float4 b0 = ((const float4*)p1)[0], b1 = ((const float4*)p1)[1];
    f16x8 h0 = { (_Float16)a0.x, (_Float16)a0.y, (_Float16)a0.z, (_Float16)a0.w,
                 (_Float16)a1.x, (_Float16)a1.y, (_Float16)a1.z, (_Float16)a1.w };
    f16x8 h1 = { (_Float16)b0.x, (_Float16)b0.y, (_Float16)b0.z, (_Float16)b0.w,
                 (_Float16)b1.x, (_Float16)b1.y, (_Float16)b1.z, (_Float16)b1.w };
    *(f16x8*)&Eh[n * QDIM + k] = h0;
    *(f16x8*)&Eh[(n + QBATCH) * QDIM + k] = h1;
    float g[8] = { c0*a0.x + c1*b0.x, c0*a0.y + c1*b0.y, c0*a0.z + c1*b0.z, c0*a0.w + c1*b0.w,
                   c0*a1.x + c1*b1.x, c0*a1.y + c1*b1.y, c0*a1.z + c1*b1.z, c0*a1.w + c1*b1.w };
    int2 gp = { pack4_i8(q8(g[0]*qs), q8(g[1]*qs), q8(g[2]*qs), q8(g[3]*qs)),
                pack4_i8(q8(g[4]*qs), q8(g[5]*qs), q8(g[6]*qs), q8(g[7]*qs)) };
    *(int2*)&G8[n * QDIM + k] = gp;
}

// ---------------------------------------------------------------------------
// Expand: A1[b,idx]=f16(Re v), A1[b+2048,idx]=f16(Im v). Prefix over top 8 bits.
// ---------------------------------------------------------------------------
__global__ __launch_bounds__(256) void expand_kernel(
    const float* __restrict__ inputs, _Float16* __restrict__ A1)
{
    __shared__ float ab[NQ][4];
    const int b = blockIdx.x;
    const int tid = threadIdx.x;
    if (tid < NQ) {
        float x = inputs[b * NQ + tid];
        float ry = 0.5f * x;
        float rz = 0.5f * x * x;
        float ca = cosf(ry), sa = sinf(ry), cz = cosf(rz), sz = sinf(rz);
        ab[tid][0] = ca * cz;  ab[tid][1] = -ca * sz;
        ab[tid][2] = sa * cz;  ab[tid][3] =  sa * sz;
    }
    __syncthreads();
    float pr0 = 1.f, pi0 = 0.f;
#pragma unroll
    for (int q = 0; q < 8; ++q) {
        int bit = (tid >> (7 - q)) & 1;
        float cr = ab[q][bit * 2 + 0], ci = ab[q][bit * 2 + 1];
        float nr = pr0 * cr - pi0 * ci;
        float ni = pr0 * ci + pi0 * cr;
        pr0 = nr; pi0 = ni;
    }
    f16x8 vr[2], vi[2];
#pragma unroll
    for (int u = 0; u < 16; ++u) {
        float pr = pr0, pi = pi0;
#pragma unroll
        for (int q = 8; q < 12; ++q) {
            int bit = (u >> (11 - q)) & 1;
            float cr = ab[q][bit * 2 + 0], ci = ab[q][bit * 2 + 1];
            float nr = pr * cr - pi * ci;
            float ni = pr * ci + pi * cr;
            pr = nr; pi = ni;
        }
        vr[u >> 3][u & 7] = (_Float16)pr;
        vi[u >> 3][u & 7] = (_Float16)pi;
    }
    const int idx0 = tid * 16;
    *(f16x8*)&A1[(size_t)b * QDIM + idx0] = vr[0];
    *(f16x8*)&A1[(size_t)b * QDIM + idx0 + 8] = vr[1];
    *(f16x8*)&A1[(size_t)(b + QBATCH) * QDIM + idx0] = vi[0];
    *(f16x8*)&A1[(size_t)(b + QBATCH) * QDIM + idx0 + 8] = vi[1];
}

// ---------------------------------------------------------------------------
// GEMM1 (f16, proven): C[m,n] = sum_k A[m,k]*B[n,k]. 128x128 tile, BK=64,
// XOR-swizzled LDS (0 conflicts), 4 waves 2x2, 4x4 16x16x32 acc per wave.
// ---------------------------------------------------------------------------
__global__ __launch_bounds__(256) void gemm_f16(
    const _Float16* __restrict__ A, const _Float16* __restrict__ B,
    _Float16* __restrict__ C, int N)
{
    const int K = QDIM;
    __shared__ __attribute__((aligned(16))) _Float16 As[128 * 64];
    __shared__ __attribute__((aligned(16))) _Float16 Bs[128 * 64];

    const int tid  = threadIdx.x;
    const int wave = tid >> 6;
    const int lane = tid & 63;
    const int bn0 = blockIdx.x * 128;
    const int bm0 = blockIdx.y * 128;
    const int wm = (wave >> 1) * 64;
    const int wn = (wave & 1) * 64;
    const int q = lane >> 4;
    const int r = lane & 15;
    const int rx = r & 7;

    f32x4 acc[4][4];
#pragma unroll
    for (int i = 0; i < 4; ++i)
#pragma unroll
        for (int j = 0; j < 4; ++j) acc[i][j] = (f32x4){0.f, 0.f, 0.f, 0.f};

    const _Float16* gA[4];
    const _Float16* gB[4];
    char* lA[4];
    char* lB[4];
#pragma unroll
    for (int n = 0; n < 4; ++n) {
        int c = n * 256 + tid;
        int row = c >> 3;
        int gcol = (c & 7) ^ (row & 7);
        gA[n] = A + (size_t)(bm0 + row) * K + gcol * 8;
        gB[n] = B + (size_t)(bn0 + row) * K + gcol * 8;
        lA[n] = (char*)As + (n * 256 + wave * 64) * 16;
        lB[n] = (char*)Bs + (n * 256 + wave * 64) * 16;
    }

    for (int kk = 0; kk < K; kk += 64) {
#pragma unroll
        for (int n = 0; n < 4; ++n) {
            gld_lds16(gA[n] + kk, lA[n]);
            gld_lds16(gB[n] + kk, lB[n]);
        }
        __syncthreads();

#pragma unroll
        for (int s = 0; s < 2; ++s) {
            f16x8 af[4], bf[4];
#pragma unroll
            for (int i = 0; i < 4; ++i) {
                int row = wm + i * 16 + r;
                af[i] = *(const f16x8*)&As[(row * 8 + ((s * 4 + q) ^ rx)) * 8];
            }
#pragma unroll
            for (int j = 0; j < 4; ++j) {
                int row = wn + j * 16 + r;
                bf[j] = *(const f16x8*)&Bs[(row * 8 + ((s * 4 + q) ^ rx)) * 8];
            }
#pragma unroll
            for (int i = 0; i < 4; ++i)
#pragma unroll
                for (int j = 0; j < 4; ++j)
                    acc[i][j] = __builtin_amdgcn_mfma_f32_16x16x32_f16(af[i], bf[j], acc[i][j], 0, 0, 0);
        }
        __syncthreads();
    }

#pragma unroll
    for (int i = 0; i < 4; ++i) {
        const int crow = bm0 + wm + i * 16 + q * 4;
#pragma unroll
        for (int rr = 0; rr < 4; ++rr)
#pragma unroll
            for (int j = 0; j < 4; ++j)
                C[(size_t)(crow + rr) * N + bn0 + wn + j * 16 + r] = (_Float16)acc[i][j][rr];
    }
}

// ---------------------------------------------------------------------------
// Butterfly: u2 = R u1 per complex row; 4 stages in-register + 8 in LDS.
// Output: per-row absmax -> int8 rows A2[b], A2[b+2048]; scaleA[row]=absmax/127.
// ---------------------------------------------------------------------------
__global__ __launch_bounds__(256) void butterfly_kernel(
    const _Float16* __restrict__ u1, const float* __restrict__ wgt,
    signed char* __restrict__ A2, float* __restrict__ scaleA)
{
    __shared__ float sRe[QDIM];
    __shared__ float sIm[QDIM];
    __shared__ float mats[NQ][8];
    __shared__ float red[8];
    const int b = blockIdx.x;
    const int tid = threadIdx.x;

    if (tid < NQ) {
        float tx = 0.5f * wgt[3 + tid];
        float tz = 0.5f * wgt[15 + tid];
        float c = cosf(tx), s = sinf(tx), cz = cosf(tz), sz = sinf(tz);
        mats[tid][0] =  c * cz;  mats[tid][1] = -c * sz;
        mats[tid][2] =  s * sz;  mats[tid][3] = -s * cz;
        mats[tid][4] = -s * sz;  mats[tid][5] = -s * cz;
        mats[tid][6] =  c * cz;  mats[tid][7] =  c * sz;
    }
    // load 16 consecutive elements into registers
    const int base = tid * 16;
    const _Float16* pRe = u1 + (size_t)b * QDIM + base;
    const _Float16* pIm = u1 + (size_t)(b + QBATCH) * QDIM + base;
    float xr[16], xi[16];
    {
        f16x8 r0 = ((const f16x8*)pRe)[0], r1 = ((const f16x8*)pRe)[1];
        f16x8 i0 = ((const f16x8*)pIm)[0], i1 = ((const f16x8*)pIm)[1];
#pragma unroll
        for (int j = 0; j < 8; ++j) {
            xr[j] = (float)r0[j]; xr[8 + j] = (float)r1[j];
            xi[j] = (float)i0[j]; xi[8 + j] = (float)i1[j];
        }
    }
    __syncthreads();  // mats ready

    // stages p=0..3 (qubits 11..8): pairs within this thread's 16 elements
#pragma unroll
    for (int p = 0; p < 4; ++p) {
        const int qq = 11 - p;
        const float m00r = mats[qq][0], m00i = mats[qq][1];
        const float m01r = mats[qq][2], m01i = mats[qq][3];
        const float m10r = mats[qq][4], m10i = mats[qq][5];
        const float m11r = mats[qq][6], m11i = mats[qq][7];
#pragma unroll
        for (int t = 0; t < 8; ++t) {
            int i0 = ((t >> p) << (p + 1)) | (t & ((1 << p) - 1));
            int i1 = i0 | (1 << p);
            float x0r = xr[i0], x0i = xi[i0];
            float x1r = xr[i1], x1i = xi[i1];
            xr[i0] = m00r * x0r - m00i * x0i + m01r * x1r - m01i * x1i;
            xi[i0] = m00r * x0i + m00i * x0r + m01r * x1i + m01i * x1r;
            xr[i1] = m10r * x0r - m10i * x0i + m11r * x1r - m11i * x1i;
            xi[i1] = m10r * x0i + m10i * x0r + m11r * x1i + m11i * x1r;
        }
    }
#pragma unroll
    for (int j = 0; j < 16; ++j) { sRe[base + j] = xr[j]; sIm[base + j] = xi[j]; }
    __syncthreads();

    // stages p=4..11 in LDS
    for (int p = 4; p < 12; ++p) {
        const int qq = 11 - p;
        const float m00r = mats[qq][0], m00i = mats[qq][1];
        const float m01r = mats[qq][2], m01i = mats[qq][3];
        const float m10r = mats[qq][4], m10i = mats[qq][5];
        const float m11r = mats[qq][6], m11i = mats[qq][7];
        for (int t = tid; t < QDIM / 2; t += 256) {
            int i0 = ((t >> p) << (p + 1)) | (t & ((1 << p) - 1));
            int i1 = i0 | (1 << p);
            float x0r = sRe[i0], x0i = sIm[i0];
            float x1r = sRe[i1], x1i = sIm[i1];
            sRe[i0] = m00r * x0r - m00i * x0i + m01r * x1r - m01i * x1i;
            sIm[i0] = m00r * x0i + m00i * x0r + m01r * x1i + m01i * x1r;
            sRe[i1] = m10r * x0r - m10i * x0i + m11r * x1r - m11i * x1i;
            sIm[i1] = m10r * x0i + m10i * x0r + m11r * x1i + m11i * x1r;
        }
        __syncthreads();
    }

    // per-row absmax (Re row b, Im row b+2048)
    float mR = 0.f, mI = 0.f;
#pragma unroll
    for (int j = 0; j < 16; ++j) {
        mR = fmaxf(mR, fabsf(sRe[base + j]));
        mI = fmaxf(mI, fabsf(sIm[base + j]));
    }
#pragma unroll
    for (int off = 32; off > 0; off >>= 1) {
        mR = fmaxf(mR, __shfl_xor(mR, off, 64));
        mI = fmaxf(mI, __shfl_xor(mI, off, 64));
    }
    const int wid = tid >> 6;
    if ((tid & 63) == 0) { red[wid] = mR; red[4 + wid] = mI; }
    __syncthreads();
    mR = fmaxf(fmaxf(red[0], red[1]), fmaxf(red[2], red[3]));
    mI = fmaxf(fmaxf(red[4], red[5]), fmaxf(red[6], red[7]));
    mR = fmaxf(mR, 1e-30f);
    mI = fmaxf(mI, 1e-30f);
    if (tid == 0) {
        scaleA[b] = mR / 127.f;
        scaleA[b + QBATCH] = mI / 127.f;
    }
    const float invR = 127.f / mR, invI = 127.f / mI;
    i32x4 qr, qi;
#pragma unroll
    for (int w = 0; w < 4; ++w) {
        qr[w] = pack4_i8(q8(sRe[base + 4*w] * invR), q8(sRe[base + 4*w + 1] * invR),
                         q8(sRe[base + 4*w + 2] * invR), q8(sRe[base + 4*w + 3] * invR));
        qi[w] = pack4_i8(q8(sIm[base + 4*w] * invI), q8(sIm[base + 4*w + 1] * invI),
                         q8(sIm[base + 4*w + 2] * invI), q8(sIm[base + 4*w + 3] * invI));
    }
    *(i32x4*)&A2[(size_t)b * QDIM + base] = qr;
    *(i32x4*)&A2[(size_t)(b + QBATCH) * QDIM + base] = qi;
}

// ---------------------------------------------------------------------------
// GEMM2 (i8, fused reduce): acc[m,n] = sum_k A2[m,k]*G8[n,k] (i32);
// out[m & 2047] += sum_n (acc * scaleA[m] * dqG)^2.  Same tile/swizzle as gemm_f16,
// two mfma_i32_16x16x64_i8 per fragment pair per 128B stage.
// ---------------------------------------------------------------------------
__global__ __launch_bounds__(256) void gemm2_i8(
    const signed char* __restrict__ A, const signed char* __restrict__ B,
    const float* __restrict__ scaleA, float* __restrict__ out)
{
    const int K = QDIM;  // bytes per row
    __shared__ __attribute__((aligned(16))) signed char As[128 * 128];
    __shared__ __attribute__((aligned(16))) signed char Bs[128 * 128];

    const int tid  = threadIdx.x;
    const int wave = tid >> 6;
    const int lane = tid & 63;
    const int bn0 = blockIdx.x * 128;
    const int bm0 = blockIdx.y * 128;
    const int wm = (wave >> 1) * 64;
    const int wn = (wave & 1) * 64;
    const int q = lane >> 4;
    const int r = lane & 15;
    const int rx = r & 7;

    i32x4 acc[4][4];
#pragma unroll
    for (int i = 0; i < 4; ++i)
#pragma unroll
        for (int j = 0; j < 4; ++j) acc[i][j] = (i32x4){0, 0, 0, 0};

    const signed char* gA[4];
    const signed char* gB[4];
    char* lA[4];
    char* lB[4];
#pragma unroll
    for (int n = 0; n < 4; ++n) {
        int c = n * 256 + tid;
        int row = c >> 3;
        int gcol = (c & 7) ^ (row & 7);
        gA[n] = A + (size_t)(bm0 + row) * K + gcol * 16;
        gB[n] = B + (size_t)(bn0 + row) * K + gcol * 16;
        lA[n] = (char*)As + (n * 256 + wave * 64) * 16;
        lB[n] = (char*)Bs + (n * 256 + wave * 64) * 16;
    }

    for (int kk = 0; kk < K; kk += 128) {
#pragma unroll
        for (int n = 0; n < 4; ++n) {
            gld_lds16(gA[n] + kk, lA[n]);
            gld_lds16(gB[n] + kk, lB[n]);
        }
        __syncthreads();

#pragma unroll
        for (int s = 0; s < 2; ++s) {
            i32x4 af[4], bf[4];
#pragma unroll
            for (int i = 0; i < 4; ++i) {
                int row = wm + i * 16 + r;
                af[i] = *(const i32x4*)&As[row * 128 + (((s * 4 + q) ^ rx) * 16)];
            }
#pragma unroll
            for (int j = 0; j < 4; ++j) {
                int row = wn + j * 16 + r;
                bf[j] = *(const i32x4*)&Bs[row * 128 + (((s * 4 + q) ^ rx) * 16)];
            }
#pragma unroll
            for (int i = 0; i < 4; ++i)
#pragma unroll
                for (int j = 0; j < 4; ++j)
                    acc[i][j] = __builtin_amdgcn_mfma_i32_16x16x64_i8(af[i], bf[j], acc[i][j], 0, 0, 0);
        }
        __syncthreads();
    }

    // C/D layout: col = r, row = q*4 + reg. Fused |.|^2 reduce.
    const float dqG = 6.f / 127.f;
#pragma unroll
    for (int i = 0; i < 4; ++i) {
#pragma unroll
        for (int rr = 0; rr < 4; ++rr) {
            const int row = bm0 + wm + i * 16 + q * 4 + rr;
            const float sc = scaleA[row] * dqG;
            float v = 0.f;
#pragma unroll
            for (int j = 0; j < 4; ++j) {
                float t = sc * (float)acc[i][j][rr];
                v = fmaf(t, t, v);
            }
            v += __shfl_xor(v, 1, 64);
            v += __shfl_xor(v, 2, 64);
            v += __shfl_xor(v, 4, 64);
            v += __shfl_xor(v, 8, 64);
            if (r == 0) atomicAdd(&out[row & (QBATCH - 1)], v);
        }
    }
}

// ---------------------------------------------------------------------------
__global__ __launch_bounds__(256) void zero_out(float* __restrict__ out) {
    ((float4*)out)[blockIdx.x * 256 + threadIdx.x] = (float4){0.f, 0.f, 0.f, 0.f};
}

// ---------------------------------------------------------------------------
extern "C" void kernel_launch(void* const* d_in, const int* in_sizes, int n_in,
                              void* d_out, int out_size, void* d_ws, size_t ws_size,
                              hipStream_t stream)
{
    const float* inputs = (const float*)d_in[0];   // [2048, 12]
    const float* weight = (const float*)d_in[1];   // [27]
    const float* E      = (const float*)d_in[2];   // [4096, 4096] fp32
    float* out = (float*)d_out;                    // [2048]

    char* ws = (char*)d_ws;
    const size_t MB = 1024 * 1024;
    _Float16*    Eh     = (_Float16*)   (ws + 0);         // 32 MB f16 [4096][4096]
    signed char* G8     = (signed char*)(ws + 32 * MB);   //  8 MB i8  [2048][4096]
    _Float16*    A1     = (_Float16*)   (ws + 40 * MB);   // 32 MB f16 [4096][4096]
    _Float16*    u1     = (_Float16*)   (ws + 72 * MB);   // 32 MB f16 [4096][4096]
    signed char* A2     = (signed char*)(ws + 104 * MB);  // 16 MB i8  [4096][4096]
    float*       scaleA = (float*)      (ws + 120 * MB);  // 16 KB

    conv_kernel<<<(QBATCH * QDIM / 8) / 256, 256, 0, stream>>>(E, weight, Eh, G8);
    expand_kernel<<<QBATCH, 256, 0, stream>>>(inputs, A1);
    // u1 = v @ Eh^T  (M=4096 Re/Im stacked, N=4096, K=4096), f16 (proven path)
    gemm_f16<<<dim3(QDIM / 128, QDIM / 128), 256, 0, stream>>>(A1, Eh, u1, QDIM);
    // u2 = R u1 -> int8 rows + per-row scales
    butterfly_kernel<<<QBATCH, 256, 0, stream>>>(u1, weight, A2, scaleA);
    // out[b] = sum_n |(u2 @ G^T)[b / b+2048, n]|^2  (i8 MFMA, fused reduce)
    zero_out<<<QBATCH / 1024, 256, 0, stream>>>(out);
    gemm2_i8<<<dim3(2048 / 128, QDIM / 128), 256, 0, stream>>>(A2, G8, scaleA, out);
}

// Round 6
// 321.356 us; speedup vs baseline: 8.3799x; 1.0477x over previous
//
#include <hip/hip_runtime.h>
#include <math.h>

#define QDIM 4096
#define NQ 12
#define QBATCH 2048

typedef _Float16 f16x8 __attribute__((ext_vector_type(8)));
typedef float f32x4 __attribute__((ext_vector_type(4)));
typedef int i32x4 __attribute__((ext_vector_type(4)));

__device__ __forceinline__ void gld_lds16(const void* gptr, void* ldsptr) {
    __builtin_amdgcn_global_load_lds(
        (const __attribute__((address_space(1))) void*)gptr,
        (__attribute__((address_space(3))) void*)ldsptr,
        16, 0, 0);
}

__device__ __forceinline__ int q8(float x) {
    float y = fminf(fmaxf(x, -127.f), 127.f);
    return (int)rintf(y);
}
__device__ __forceinline__ int pack4_i8(int a, int b, int c, int d) {
    return (a & 0xFF) | ((b & 0xFF) << 8) | ((c & 0xFF) << 16) | ((d & 0xFF) << 24);
}

// ---------------------------------------------------------------------------
// conv (single pass over E): Eh = f16(E) [both halves];
// G8[n,:] = int8( (c0*E[n,:]+c1*E[n+2048,:]) * 127/6 )   (G ~ N(0,1), 6-sigma clip)
// ---------------------------------------------------------------------------
__global__ __launch_bounds__(256) void conv_kernel(
    const float* __restrict__ E, const float* __restrict__ wgt,
    _Float16* __restrict__ Eh, signed char* __restrict__ G8)
{
    float th = 0.5f * (wgt[0] + wgt[1] + wgt[2]);
    float c0 = cosf(th), c1 = -sinf(th);
    const float qs = 127.f / 6.f;
    size_t flat = ((size_t)blockIdx.x * 256 + threadIdx.x) * 8;  // [0, 2048*4096)
    size_t n = flat >> 12;
    size_t k = flat & (QDIM - 1);
    const float* p0 = E + n * QDIM + k;
    const float* p1 = p0 + (size_t)QBATCH * QDIM;
    float4 a0 = ((const float4*)p0)[0], a1 = ((const float4*)p0)[1];
    float4 b0 = ((const float4*)p1)[0], b1 = ((const float4*)p1)[1];
    f16x8 h0 = { (_Float16)a0.x, (_Float16)a0.y, (_Float16)a0.z, (_Float16)a0.w,
                 (_Float16)a1.x, (_Float16)a1.y, (_Float16)a1.z, (_Float16)a1.w };
    f16x8 h1 = { (_Float16)b0.x, (_Float16)b0.y, (_Float16)b0.z, (_Float16)b0.w,
                 (_Float16)b1.x, (_Float16)b1.y, (_Float16)b1.z, (_Float16)b1.w };
    *(f16x8*)&Eh[n * QDIM + k] = h0;
    *(f16x8*)&Eh[(n + QBATCH) * QDIM + k] = h1;
    float g[8] = { c0*a0.x + c1*b0.x, c0*a0.y + c1*b0.y, c0*a0.z + c1*b0.z, c0*a0.w + c1*b0.w,
                   c0*a1.x + c1*b1.x, c0*a1.y + c1*b1.y, c0*a1.z + c1*b1.z, c0*a1.w + c1*b1.w };
    int2 gp = { pack4_i8(q8(g[0]*qs), q8(g[1]*qs), q8(g[2]*qs), q8(g[3]*qs)),
                pack4_i8(q8(g[4]*qs), q8(g[5]*qs), q8(g[6]*qs), q8(g[7]*qs)) };
    *(int2*)&G8[n * QDIM + k] = gp;
}

// ---------------------------------------------------------------------------
// Expand: A1[b,idx]=f16(Re v), A1[b+2048,idx]=f16(Im v). Prefix over top 8 bits.
// Also zeroes out[b] (gemm2 accumulates atomically later in the stream).
// ---------------------------------------------------------------------------
__global__ __launch_bounds__(256) void expand_kernel(
    const float* __restrict__ inputs, _Float16* __restrict__ A1,
    float* __restrict__ out)
{
    __shared__ float ab[NQ][4];
    const int b = blockIdx.x;
    const int tid = threadIdx.x;
    if (tid == 0) out[b] = 0.f;
    if (tid < NQ) {
        float x = inputs[b * NQ + tid];
        float ry = 0.5f * x;
        float rz = 0.5f * x * x;
        float ca = cosf(ry), sa = sinf(ry), cz = cosf(rz), sz = sinf(rz);
        ab[tid][0] = ca * cz;  ab[tid][1] = -ca * sz;
        ab[tid][2] = sa * cz;  ab[tid][3] =  sa * sz;
    }
    __syncthreads();
    float pr0 = 1.f, pi0 = 0.f;
#pragma unroll
    for (int q = 0; q < 8; ++q) {
        int bit = (tid >> (7 - q)) & 1;
        float cr = ab[q][bit * 2 + 0], ci = ab[q][bit * 2 + 1];
        float nr = pr0 * cr - pi0 * ci;
        float ni = pr0 * ci + pi0 * cr;
        pr0 = nr; pi0 = ni;
    }
    f16x8 vr[2], vi[2];
#pragma unroll
    for (int u = 0; u < 16; ++u) {
        float pr = pr0, pi = pi0;
#pragma unroll
        for (int q = 8; q < 12; ++q) {
            int bit = (u >> (11 - q)) & 1;
            float cr = ab[q][bit * 2 + 0], ci = ab[q][bit * 2 + 1];
            float nr = pr * cr - pi * ci;
            float ni = pr * ci + pi * cr;
            pr = nr; pi = ni;
        }
        vr[u >> 3][u & 7] = (_Float16)pr;
        vi[u >> 3][u & 7] = (_Float16)pi;
    }
    const int idx0 = tid * 16;
    *(f16x8*)&A1[(size_t)b * QDIM + idx0] = vr[0];
    *(f16x8*)&A1[(size_t)b * QDIM + idx0 + 8] = vr[1];
    *(f16x8*)&A1[(size_t)(b + QBATCH) * QDIM + idx0] = vi[0];
    *(f16x8*)&A1[(size_t)(b + QBATCH) * QDIM + idx0 + 8] = vi[1];
}

// ---------------------------------------------------------------------------
// GEMM1 (f16, proven): C[m,n] = sum_k A[m,k]*B[n,k]. 128x128 tile, BK=64,
// XOR-swizzled LDS (0 conflicts), 4 waves 2x2, 4x4 16x16x32 acc per wave.
// ---------------------------------------------------------------------------
__global__ __launch_bounds__(256) void gemm_f16(
    const _Float16* __restrict__ A, const _Float16* __restrict__ B,
    _Float16* __restrict__ C, int N)
{
    const int K = QDIM;
    __shared__ __attribute__((aligned(16))) _Float16 As[128 * 64];
    __shared__ __attribute__((aligned(16))) _Float16 Bs[128 * 64];

    const int tid  = threadIdx.x;
    const int wave = tid >> 6;
    const int lane = tid & 63;
    const int bn0 = blockIdx.x * 128;
    const int bm0 = blockIdx.y * 128;
    const int wm = (wave >> 1) * 64;
    const int wn = (wave & 1) * 64;
    const int q = lane >> 4;
    const int r = lane & 15;
    const int rx = r & 7;

    f32x4 acc[4][4];
#pragma unroll
    for (int i = 0; i < 4; ++i)
#pragma unroll
        for (int j = 0; j < 4; ++j) acc[i][j] = (f32x4){0.f, 0.f, 0.f, 0.f};

    const _Float16* gA[4];
    const _Float16* gB[4];
    char* lA[4];
    char* lB[4];
#pragma unroll
    for (int n = 0; n < 4; ++n) {
        int c = n * 256 + tid;
        int row = c >> 3;
        int gcol = (c & 7) ^ (row & 7);
        gA[n] = A + (size_t)(bm0 + row) * K + gcol * 8;
        gB[n] = B + (size_t)(bn0 + row) * K + gcol * 8;
        lA[n] = (char*)As + (n * 256 + wave * 64) * 16;
        lB[n] = (char*)Bs + (n * 256 + wave * 64) * 16;
    }

    for (int kk = 0; kk < K; kk += 64) {
#pragma unroll
        for (int n = 0; n < 4; ++n) {
            gld_lds16(gA[n] + kk, lA[n]);
            gld_lds16(gB[n] + kk, lB[n]);
        }
        __syncthreads();

#pragma unroll
        for (int s = 0; s < 2; ++s) {
            f16x8 af[4], bf[4];
#pragma unroll
            for (int i = 0; i < 4; ++i) {
                int row = wm + i * 16 + r;
                af[i] = *(const f16x8*)&As[(row * 8 + ((s * 4 + q) ^ rx)) * 8];
            }
#pragma unroll
            for (int j = 0; j < 4; ++j) {
                int row = wn + j * 16 + r;
                bf[j] = *(const f16x8*)&Bs[(row * 8 + ((s * 4 + q) ^ rx)) * 8];
            }
#pragma unroll
            for (int i = 0; i < 4; ++i)
#pragma unroll
                for (int j = 0; j < 4; ++j)
                    acc[i][j] = __builtin_amdgcn_mfma_f32_16x16x32_f16(af[i], bf[j], acc[i][j], 0, 0, 0);
        }
        __syncthreads();
    }

#pragma unroll
    for (int i = 0; i < 4; ++i) {
        const int crow = bm0 + wm + i * 16 + q * 4;
#pragma unroll
        for (int rr = 0; rr < 4; ++rr)
#pragma unroll
            for (int j = 0; j < 4; ++j)
                C[(size_t)(crow + rr) * N + bn0 + wn + j * 16 + r] = (_Float16)acc[i][j][rr];
    }
}

// ---------------------------------------------------------------------------
// Butterfly v2 (3-phase register FFT): u2 = R u1 per complex row.
// idx = a*256 + b*16 + c. Phase A: stages on c-bits (in-reg, thread=(a,b)).
// Exchange via padded LDS pos = 273a + 17b + c (<=2-way banks on most sets).
// Phase B: stages on b-bits (thread=(a,c)). Phase C: stages on a-bits
// (thread=(b,c)); absmax reduce from regs; direct coalesced i8 byte stores.
// ---------------------------------------------------------------------------
__global__ __launch_bounds__(256) void butterfly_kernel(
    const _Float16* __restrict__ u1, const float* __restrict__ wgt,
    signed char* __restrict__ A2, float* __restrict__ scaleA)
{
    __shared__ float sRe[4366];
    __shared__ float sIm[4366];
    __shared__ float mats[NQ][8];
    __shared__ float red[8];
    const int blk = blockIdx.x;
    const int tid = threadIdx.x;
    const int ah = tid >> 4;    // phase A/B: a  | phase C: b
    const int al = tid & 15;    // phase A: b    | phase B/C: c

    if (tid < NQ) {
        float tx = 0.5f * wgt[3 + tid];
        float tz = 0.5f * wgt[15 + tid];
        float c = cosf(tx), s = sinf(tx), cz = cosf(tz), sz = sinf(tz);
        mats[tid][0] =  c * cz;  mats[tid][1] = -c * sz;
        mats[tid][2] =  s * sz;  mats[tid][3] = -s * cz;
        mats[tid][4] = -s * sz;  mats[tid][5] = -s * cz;
        mats[tid][6] =  c * cz;  mats[tid][7] =  c * sz;
    }

    // load 16 consecutive elements (idx = tid*16 + c)
    float xr[16], xi[16];
    {
        const _Float16* pRe = u1 + (size_t)blk * QDIM + tid * 16;
        const _Float16* pIm = u1 + (size_t)(blk + QBATCH) * QDIM + tid * 16;
        f16x8 r0 = ((const f16x8*)pRe)[0], r1 = ((const f16x8*)pRe)[1];
        f16x8 i0 = ((const f16x8*)pIm)[0], i1 = ((const f16x8*)pIm)[1];
#pragma unroll
        for (int j = 0; j < 8; ++j) {
            xr[j] = (float)r0[j]; xr[8 + j] = (float)r1[j];
            xi[j] = (float)i0[j]; xi[8 + j] = (float)i1[j];
        }
    }
    __syncthreads();  // mats ready

#define BFLY_STAGE(arrR, arrI, K_, Q_)                                         \
    {                                                                          \
        const float m00r = mats[Q_][0], m00i = mats[Q_][1];                    \
        const float m01r = mats[Q_][2], m01i = mats[Q_][3];                    \
        const float m10r = mats[Q_][4], m10i = mats[Q_][5];                    \
        const float m11r = mats[Q_][6], m11i = mats[Q_][7];                    \
        _Pragma("unroll")                                                      \
        for (int t = 0; t < 8; ++t) {                                          \
            int i0 = ((t >> (K_)) << ((K_) + 1)) | (t & ((1 << (K_)) - 1));    \
            int i1 = i0 | (1 << (K_));                                         \
            float x0r = arrR[i0], x0i = arrI[i0];                              \
            float x1r = arrR[i1], x1i = arrI[i1];                              \
            arrR[i0] = m00r * x0r - m00i * x0i + m01r * x1r - m01i * x1i;      \
            arrI[i0] = m00r * x0i + m00i * x0r + m01r * x1i + m01i * x1r;      \
            arrR[i1] = m10r * x0r - m10i * x0i + m11r * x1r - m11i * x1i;      \
            arrI[i1] = m10r * x0i + m10i * x0r + m11r * x1i + m11i * x1r;      \
        }                                                                      \
    }

    // Phase A: idx bits 0..3 (c), qubits 11..8
#pragma unroll
    for (int p = 0; p < 4; ++p) BFLY_STAGE(xr, xi, p, 11 - p);

    // Exchange 1: thread (a=ah, b=al) writes its c-line
#pragma unroll
    for (int c = 0; c < 16; ++c) {
        sRe[273 * ah + 17 * al + c] = xr[c];
        sIm[273 * ah + 17 * al + c] = xi[c];
    }
    __syncthreads();

    // Phase B: thread (a=ah, c=al) reads b-line; stages on idx bits 4..7
    float yr[16], yi[16];
#pragma unroll
    for (int b = 0; b < 16; ++b) {
        yr[b] = sRe[273 * ah + 17 * b + al];
        yi[b] = sIm[273 * ah + 17 * b + al];
    }
#pragma unroll
    for (int p = 0; p < 4; ++p) BFLY_STAGE(yr, yi, p, 7 - p);

    // Exchange 2: same positions this thread read — no barrier needed before write
#pragma unroll
    for (int b = 0; b < 16; ++b) {
        sRe[273 * ah + 17 * b + al] = yr[b];
        sIm[273 * ah + 17 * b + al] = yi[b];
    }
    __syncthreads();

    // Phase C: thread (b=ah, c=al) reads a-line; stages on idx bits 8..11
    float zr[16], zi[16];
#pragma unroll
    for (int a = 0; a < 16; ++a) {
        zr[a] = sRe[273 * a + 17 * ah + al];
        zi[a] = sIm[273 * a + 17 * ah + al];
    }
#pragma unroll
    for (int p = 0; p < 4; ++p) BFLY_STAGE(zr, zi, p, 3 - p);

    // per-row absmax from registers
    float mR = 0.f, mI = 0.f;
#pragma unroll
    for (int j = 0; j < 16; ++j) {
        mR = fmaxf(mR, fabsf(zr[j]));
        mI = fmaxf(mI, fabsf(zi[j]));
    }
#pragma unroll
    for (int off = 32; off > 0; off >>= 1) {
        mR = fmaxf(mR, __shfl_xor(mR, off, 64));
        mI = fmaxf(mI, __shfl_xor(mI, off, 64));
    }
    const int wid = tid >> 6;
    if ((tid & 63) == 0) { red[wid] = mR; red[4 + wid] = mI; }
    __syncthreads();
    mR = fmaxf(fmaxf(red[0], red[1]), fmaxf(red[2], red[3]));
    mI = fmaxf(fmaxf(red[4], red[5]), fmaxf(red[6], red[7]));
    mR = fmaxf(mR, 1e-30f);
    mI = fmaxf(mI, 1e-30f);
    if (tid == 0) {
        scaleA[blk] = mR / 127.f;
        scaleA[blk + QBATCH] = mI / 127.f;
    }
    const float invR = 127.f / mR, invI = 127.f / mI;

    // store: element idx = a*256 + ah*16 + al -> per-a instr covers 64
    // consecutive bytes per wave (coalesced byte stores)
    signed char* oRe = A2 + (size_t)blk * QDIM + ah * 16 + al;
    signed char* oIm = A2 + (size_t)(blk + QBATCH) * QDIM + ah * 16 + al;
#pragma unroll
    for (int a = 0; a < 16; ++a) {
        oRe[a * 256] = (signed char)q8(zr[a] * invR);
        oIm[a * 256] = (signed char)q8(zi[a] * invI);
    }
#undef BFLY_STAGE
}

// ---------------------------------------------------------------------------
// GEMM2 (i8, fused reduce): acc[m,n] = sum_k A2[m,k]*G8[n,k] (i32);
// out[m & 2047] += sum_n (acc * scaleA[m] * dqG)^2.  Same tile/swizzle as gemm_f16,
// two mfma_i32_16x16x64_i8 per fragment pair per 128B stage.
// ---------------------------------------------------------------------------
__global__ __launch_bounds__(256) void gemm2_i8(
    const signed char* __restrict__ A, const signed char* __restrict__ B,
    const float* __restrict__ scaleA, float* __restrict__ out)
{
    const int K = QDIM;  // bytes per row
    __shared__ __attribute__((aligned(16))) signed char As[128 * 128];
    __shared__ __attribute__((aligned(16))) signed char Bs[128 * 128];

    const int tid  = threadIdx.x;
    const int wave = tid >> 6;
    const int lane = tid & 63;
    const int bn0 = blockIdx.x * 128;
    const int bm0 = blockIdx.y * 128;
    const int wm = (wave >> 1) * 64;
    const int wn = (wave & 1) * 64;
    const int q = lane >> 4;
    const int r = lane & 15;
    const int rx = r & 7;

    i32x4 acc[4][4];
#pragma unroll
    for (int i = 0; i < 4; ++i)
#pragma unroll
        for (int j = 0; j < 4; ++j) acc[i][j] = (i32x4){0, 0, 0, 0};

    const signed char* gA[4];
    const signed char* gB[4];
    char* lA[4];
    char* lB[4];
#pragma unroll
    for (int n = 0; n < 4; ++n) {
        int c = n * 256 + tid;
        int row = c >> 3;
        int gcol = (c & 7) ^ (row & 7);
        gA[n] = A + (size_t)(bm0 + row) * K + gcol * 16;
        gB[n] = B + (size_t)(bn0 + row) * K + gcol * 16;
        lA[n] = (char*)As + (n * 256 + wave * 64) * 16;
        lB[n] = (char*)Bs + (n * 256 + wave * 64) * 16;
    }

    for (int kk = 0; kk < K; kk += 128) {
#pragma unroll
        for (int n = 0; n < 4; ++n) {
            gld_lds16(gA[n] + kk, lA[n]);
            gld_lds16(gB[n] + kk, lB[n]);
        }
        __syncthreads();

#pragma unroll
        for (int s = 0; s < 2; ++s) {
            i32x4 af[4], bf[4];
#pragma unroll
            for (int i = 0; i < 4; ++i) {
                int row = wm + i * 16 + r;
                af[i] = *(const i32x4*)&As[row * 128 + (((s * 4 + q) ^ rx) * 16)];
            }
#pragma unroll
            for (int j = 0; j < 4; ++j) {
                int row = wn + j * 16 + r;
                bf[j] = *(const i32x4*)&Bs[row * 128 + (((s * 4 + q) ^ rx) * 16)];
            }
#pragma unroll
            for (int i = 0; i < 4; ++i)
#pragma unroll
                for (int j = 0; j < 4; ++j)
                    acc[i][j] = __builtin_amdgcn_mfma_i32_16x16x64_i8(af[i], bf[j], acc[i][j], 0, 0, 0);
        }
        __syncthreads();
    }

    // C/D layout: col = r, row = q*4 + reg. Fused |.|^2 reduce.
    const float dqG = 6.f / 127.f;
#pragma unroll
    for (int i = 0; i < 4; ++i) {
#pragma unroll
        for (int rr = 0; rr < 4; ++rr) {
            const int row = bm0 + wm + i * 16 + q * 4 + rr;
            const float sc = scaleA[row] * dqG;
            float v = 0.f;
#pragma unroll
            for (int j = 0; j < 4; ++j) {
                float t = sc * (float)acc[i][j][rr];
                v = fmaf(t, t, v);
            }
            v += __shfl_xor(v, 1, 64);
            v += __shfl_xor(v, 2, 64);
            v += __shfl_xor(v, 4, 64);
            v += __shfl_xor(v, 8, 64);
            if (r == 0) atomicAdd(&out[row & (QBATCH - 1)], v);
        }
    }
}

// ---------------------------------------------------------------------------
extern "C" void kernel_launch(void* const* d_in, const int* in_sizes, int n_in,
                              void* d_out, int out_size, void* d_ws, size_t ws_size,
                              hipStream_t stream)
{
    const float* inputs = (const float*)d_in[0];   // [2048, 12]
    const float* weight = (const float*)d_in[1];   // [27]
    const float* E      = (const float*)d_in[2];   // [4096, 4096] fp32
    float* out = (float*)d_out;                    // [2048]

    char* ws = (char*)d_ws;
    const size_t MB = 1024 * 1024;
    _Float16*    Eh     = (_Float16*)   (ws + 0);         // 32 MB f16 [4096][4096]
    signed char* G8     = (signed char*)(ws + 32 * MB);   //  8 MB i8  [2048][4096]
    _Float16*    A1     = (_Float16*)   (ws + 40 * MB);   // 32 MB f16 [4096][4096]
    _Float16*    u1     = (_Float16*)   (ws + 72 * MB);   // 32 MB f16 [4096][4096]
    signed char* A2     = (signed char*)(ws + 104 * MB);  // 16 MB i8  [4096][4096]
    float*       scaleA = (float*)      (ws + 120 * MB);  // 16 KB

    conv_kernel<<<(QBATCH * QDIM / 8) / 256, 256, 0, stream>>>(E, weight, Eh, G8);
    expand_kernel<<<QBATCH, 256, 0, stream>>>(inputs, A1, out);
    // u1 = v @ Eh^T  (M=4096 Re/Im stacked, N=4096, K=4096), f16 (proven path)
    gemm_f16<<<dim3(QDIM / 128, QDIM / 128), 256, 0, stream>>>(A1, Eh, u1, QDIM);
    // u2 = R u1 -> int8 rows + per-row scales (3-phase register FFT)
    butterfly_kernel<<<QBATCH, 256, 0, stream>>>(u1, weight, A2, scaleA);
    // out[b] = sum_n |(u2 @ G^T)[b / b+2048, n]|^2  (i8 MFMA, fused reduce)
    gemm2_i8<<<dim3(2048 / 128, QDIM / 128), 256, 0, stream>>>(A2, G8, scaleA, out);
}